// Round 12
// baseline (143.733 us; speedup 1.0000x reference)
//
#include <hip/hip_runtime.h>
#include <hip/hip_bf16.h>
#include <hip/hip_fp16.h>

#define IN_CH 128
#define OUT_CH 64
#define NB 256          // edge-chunk blocks for histo/bucket_scatter (chunk = 3125)
#define CHUNK_CAP 3200  // LDS staging capacity in bucket_scatter
#define SORT_CAP 6144   // LDS staging capacity in bucket_sort (mean bucket = 4096)

typedef _Float16 hh2 __attribute__((ext_vector_type(2)));   // native half2 for v_dot2

// ======================= preprocessing: byte-identical R3 (≈9 µs total) =======================

__global__ void __launch_bounds__(512) histo_kernel(const int* __restrict__ col,
                                                    int* __restrict__ blkcnt,
                                                    int* __restrict__ rawcnt,
                                                    int E, int chunk) {
    __shared__ int h[256];
    int blk = blockIdx.x, tid = threadIdx.x;
    if (tid < 256) h[tid] = 0;
    __syncthreads();
    int s = blk * chunk, e = min(s + chunk, E);
    for (int i = s + tid; i < e; i += 512)
        atomicAdd(&h[col[i] >> 8], 1);          // LDS atomic
    __syncthreads();
    if (tid < 256) {
        blkcnt[blk * 256 + tid] = h[tid];       // coalesced
        rawcnt[blk * 256 + tid] = h[tid];
    }
}

__global__ void __launch_bounds__(256) scanblk_kernel(int* __restrict__ blkcnt,
                                                      int* __restrict__ totals) {
    __shared__ int ps[256];
    int b = blockIdx.x, tid = threadIdx.x;
    int i0 = tid * 256 + b;
    int a0 = blkcnt[i0];
    ps[tid] = a0;
    __syncthreads();
    for (int d = 1; d < 256; d <<= 1) {
        int t = 0;
        if (tid >= d) t = ps[tid - d];
        __syncthreads();
        if (tid >= d) ps[tid] += t;
        __syncthreads();
    }
    blkcnt[i0] = ps[tid] - a0;                  // exclusive within-bucket offset
    if (tid == 255) totals[b] = ps[255];
}

__global__ void __launch_bounds__(512) bucket_scatter_kernel(const int* __restrict__ row,
                                                             const int* __restrict__ col,
                                                             const int* __restrict__ blkcnt,
                                                             const int* __restrict__ rawcnt,
                                                             const int* __restrict__ totals,
                                                             unsigned int* __restrict__ tmp,
                                                             int E, int chunk, int nbkt) {
    __shared__ int ps[256];
    __shared__ int ls[256];
    __shared__ int bias[256];
    __shared__ int curl[256];
    __shared__ unsigned int vall[CHUNK_CAP];
    __shared__ int destl[CHUNK_CAP];
    int blk = blockIdx.x, tid = threadIdx.x;
    int t0 = 0, lr = 0;
    if (tid < 256) {
        t0 = (tid < nbkt) ? totals[tid] : 0;
        ps[tid] = t0;
        lr = rawcnt[blk * 256 + tid];
        ls[tid] = lr;
    }
    __syncthreads();
    for (int d = 1; d < 256; d <<= 1) {
        int t = 0, u = 0;
        if (tid < 256 && tid >= d) { t = ps[tid - d]; u = ls[tid - d]; }
        __syncthreads();
        if (tid < 256 && tid >= d) { ps[tid] += t; ls[tid] += u; }
        __syncthreads();
    }
    if (tid < 256) {
        int bucket_base = ps[tid] - t0;
        int loff = ls[tid] - lr;
        bias[tid] = bucket_base + blkcnt[blk * 256 + tid] - loff;
        curl[tid] = loff;
    }
    __syncthreads();
    int s = blk * chunk, e = min(s + chunk, E);
    int csize = e - s;
    if (csize <= CHUNK_CAP) {
        for (int i = s + tid; i < e; i += 512) {
            int c = col[i], r = row[i];
            int k = c >> 8;
            int p = atomicAdd(&curl[k], 1);
            vall[p]  = ((unsigned)(c & 255) << 16) | (unsigned)r;
            destl[p] = bias[k] + p;
        }
        __syncthreads();
        for (int j = tid; j < csize; j += 512)
            tmp[destl[j]] = vall[j];
    } else {
        for (int i = s + tid; i < e; i += 512) {
            int c = col[i], r = row[i];
            int k = c >> 8;
            int p = atomicAdd(&curl[k], 1);
            tmp[bias[k] + p] = ((unsigned)(c & 255) << 16) | (unsigned)r;
        }
    }
}

__global__ void __launch_bounds__(512) bucket_sort_kernel(const unsigned int* __restrict__ tmp,
                                                          const int* __restrict__ totals,
                                                          int* __restrict__ off,
                                                          float* __restrict__ dis,
                                                          unsigned short* __restrict__ eidx,
                                                          int nbkt, int E, int n) {
    __shared__ int bs[256];
    __shared__ int cntl[256];
    __shared__ int sc[256];
    __shared__ int posr[256];
    __shared__ unsigned short el[SORT_CAP];
    int b = blockIdx.x, tid = threadIdx.x;
    int v = 0;
    if (tid < 256) { v = (tid < nbkt) ? totals[tid] : 0; bs[tid] = v; }
    __syncthreads();
    for (int d = 1; d < 256; d <<= 1) {
        int t = 0;
        if (tid < 256 && tid >= d) t = bs[tid - d];
        __syncthreads();
        if (tid < 256 && tid >= d) bs[tid] += t;
        __syncthreads();
    }
    if (tid < 256) bs[tid] -= v;
    if (tid < 256) cntl[tid] = 0;
    __syncthreads();
    int s = bs[b];
    int cnt = (b < nbkt) ? totals[b] : 0;
    int e = s + cnt;
    for (int i = s + tid; i < e; i += 512)
        atomicAdd(&cntl[tmp[i] >> 16], 1);
    __syncthreads();
    int c = 0;
    if (tid < 256) { c = cntl[tid]; sc[tid] = c; }
    __syncthreads();
    for (int d = 1; d < 256; d <<= 1) {
        int t = 0;
        if (tid < 256 && tid >= d) t = sc[tid - d];
        __syncthreads();
        if (tid < 256 && tid >= d) sc[tid] += t;
        __syncthreads();
    }
    if (tid < 256) {
        int excl = sc[tid] - c;
        int gid = (b << 8) + tid;
        if (gid < n) {
            off[gid] = s + excl;
            dis[gid] = rsqrtf((float)(c + 1));   // +1 self-loop (gcn_norm)
        }
        posr[tid] = excl;
    }
    if (b == 0 && tid == 0) off[n] = E;
    __syncthreads();
    bool staged = (cnt <= SORT_CAP);
    if (staged) {
        for (int i = s + tid; i < e; i += 512) {
            unsigned int w = tmp[i];
            int p = atomicAdd(&posr[w >> 16], 1);
            el[p] = (unsigned short)(w & 0xFFFFu);
        }
        __syncthreads();
        for (int i = tid; i < cnt; i += 512)
            eidx[s + i] = el[i];
    } else {
        for (int i = s + tid; i < e; i += 512) {
            unsigned int w = tmp[i];
            int p = atomicAdd(&posr[w >> 16], 1);
            eidx[s + p] = (unsigned short)(w & 0xFFFFu);
        }
    }
}

// ---------------- z = fp16( dis * (X @ W^T) ) : byte-identical R3 ----------------
__global__ void __launch_bounds__(256) gemm_kernel(const float* __restrict__ x,
                                                   const float* __restrict__ W,
                                                   const float* __restrict__ dis,
                                                   __half* __restrict__ z, int n) {
    __shared__ hh2 Xs[64 * 66];
    __shared__ hh2 Ws[64 * 66];
    int t = threadIdx.x;
    int m0 = blockIdx.x * 64;
#pragma unroll
    for (int r = 0; r < 8; ++r) {
        int f = t + 256 * r;
        int o = f >> 5, kq = f & 31;
        float4 w = ((const float4*)W)[f];
        Ws[o * 66 + kq * 2]     = hh2{(_Float16)w.x, (_Float16)w.y};
        Ws[o * 66 + kq * 2 + 1] = hh2{(_Float16)w.z, (_Float16)w.w};
    }
#pragma unroll
    for (int r = 0; r < 8; ++r) {
        int f = t + 256 * r;
        int node = f >> 5, kq = f & 31;
        int gv = min(m0 + node, n - 1);
        float4 xv = ((const float4*)(x + (size_t)gv * IN_CH))[kq];
        Xs[node * 66 + kq * 2]     = hh2{(_Float16)xv.x, (_Float16)xv.y};
        Xs[node * 66 + kq * 2 + 1] = hh2{(_Float16)xv.z, (_Float16)xv.w};
    }
    __syncthreads();
    int tx = t & 15, ty = t >> 4;
    float acc[4][4];
#pragma unroll
    for (int i = 0; i < 4; ++i)
#pragma unroll
        for (int j = 0; j < 4; ++j) acc[i][j] = 0.f;

#pragma unroll 4
    for (int kq = 0; kq < 32; ++kq) {
        hh2 xa0[4], xa1[4], wb0[4], wb1[4];
#pragma unroll
        for (int i = 0; i < 4; ++i) {
            int base = (tx + 16 * i) * 66 + kq * 2;
            xa0[i] = Xs[base]; xa1[i] = Xs[base + 1];
        }
#pragma unroll
        for (int j = 0; j < 4; ++j) {
            int base = (ty * 4 + j) * 66 + kq * 2;
            wb0[j] = Ws[base]; wb1[j] = Ws[base + 1];
        }
#pragma unroll
        for (int i = 0; i < 4; ++i)
#pragma unroll
            for (int j = 0; j < 4; ++j) {
                float s = acc[i][j];
                s = __builtin_amdgcn_fdot2(xa0[i], wb0[j], s, false);
                s = __builtin_amdgcn_fdot2(xa1[i], wb1[j], s, false);
                acc[i][j] = s;
            }
    }
#pragma unroll
    for (int i = 0; i < 4; ++i) {
        int v = m0 + tx + 16 * i;
        if (v < n) {
            float dv = dis[v];
            union { __half2 h[2]; float2 f; } u;
            u.h[0] = __floats2half2_rn(dv * acc[i][0], dv * acc[i][1]);
            u.h[1] = __floats2half2_rn(dv * acc[i][2], dv * acc[i][3]);
            *(float2*)&z[(size_t)v * OUT_CH + ty * 4] = u.f;
        }
    }
}

// ============================================================================
// Hop v4: QUARTER-WAVE per node (4 nodes/wave — per-node wave-inst ~78 vs 105).
// Per node: 2 edge slots x 8 sub-chunks (16B each of the 128B row).
// 24 edges in flight per node (12 batches; P[deg>24] ~ 8%/node), pipelined tail.
// Reduce: ONE shuffle round (xor 8 — stays inside the 16-lane quarter).
// MODE 0: out(half) = dis^2 * t;  MODE 1: out(float) = dis * t + bias.
// ============================================================================
#define ACC8(raw) { const __half2* h2_ = (const __half2*)&(raw);              \
    float2 f0_ = __half22float2(h2_[0]), f1_ = __half22float2(h2_[1]);        \
    float2 f2_ = __half22float2(h2_[2]), f3_ = __half22float2(h2_[3]);        \
    a0 += f0_.x; a1 += f0_.y; a2 += f1_.x; a3 += f1_.y;                       \
    a4 += f2_.x; a5 += f2_.y; a6 += f3_.x; a7 += f3_.y; }

template <int MODE>
__global__ void __launch_bounds__(256) hop_kernel(const __half* __restrict__ zin,
                                                  void* __restrict__ out,
                                                  const unsigned short* __restrict__ eidx,
                                                  const int* __restrict__ off,
                                                  const float* __restrict__ dis,
                                                  const float* __restrict__ bias, int n) {
    int v = (int)((blockIdx.x * 256 + threadIdx.x) >> 4);   // 16-lane group = node
    if (v >= n) return;
    int l = threadIdx.x & 15;
    int grp = l >> 3;          // edge slot (2 per node)
    int sub = l & 7;           // 16B chunk of the 128B row
    int s = off[v], e = off[v + 1];
    float dv = dis[v];
    float a0 = 0.f, a1 = 0.f, a2 = 0.f, a3 = 0.f;
    float a4 = 0.f, a5 = 0.f, a6 = 0.f, a7 = 0.f;
    if (grp == 0) {            // self-loop term (z already carries dis scaling)
        float4 raw = ((const float4*)(zin + (size_t)v * OUT_CH))[sub];
        ACC8(raw);
    }
    // ---- 24 edges in flight: 12 predicated batches of 2 slots ----
    int i0 = s + grp;
    int i1 = i0 + 2,  i2 = i0 + 4,  i3 = i0 + 6,  i4 = i0 + 8,  i5 = i0 + 10;
    int i6 = i0 + 12, i7 = i0 + 14, i8 = i0 + 16, i9 = i0 + 18, i10 = i0 + 20, i11 = i0 + 22;
    bool h0 = i0 < e, h1 = i1 < e, h2 = i2 < e, h3 = i3 < e, h4 = i4 < e, h5 = i5 < e;
    bool h6 = i6 < e, h7 = i7 < e, h8 = i8 < e, h9 = i9 < e, h10 = i10 < e, h11 = i11 < e;
    int r0 = h0 ? (int)eidx[i0] : 0;
    int r1 = h1 ? (int)eidx[i1] : 0;
    int r2 = h2 ? (int)eidx[i2] : 0;
    int r3 = h3 ? (int)eidx[i3] : 0;
    int r4 = h4 ? (int)eidx[i4] : 0;
    int r5 = h5 ? (int)eidx[i5] : 0;
    int r6 = h6 ? (int)eidx[i6] : 0;
    int r7 = h7 ? (int)eidx[i7] : 0;
    int r8 = h8 ? (int)eidx[i8] : 0;
    int r9 = h9 ? (int)eidx[i9] : 0;
    int r10 = h10 ? (int)eidx[i10] : 0;
    int r11 = h11 ? (int)eidx[i11] : 0;
    {   // first 6 batches
        float4 rA = make_float4(0.f, 0.f, 0.f, 0.f);
        float4 rB = make_float4(0.f, 0.f, 0.f, 0.f);
        float4 rC = make_float4(0.f, 0.f, 0.f, 0.f);
        float4 rD = make_float4(0.f, 0.f, 0.f, 0.f);
        float4 rE = make_float4(0.f, 0.f, 0.f, 0.f);
        float4 rF = make_float4(0.f, 0.f, 0.f, 0.f);
        if (h0) rA = ((const float4*)(zin + (size_t)r0 * OUT_CH))[sub];
        if (h1) rB = ((const float4*)(zin + (size_t)r1 * OUT_CH))[sub];
        if (h2) rC = ((const float4*)(zin + (size_t)r2 * OUT_CH))[sub];
        if (h3) rD = ((const float4*)(zin + (size_t)r3 * OUT_CH))[sub];
        if (h4) rE = ((const float4*)(zin + (size_t)r4 * OUT_CH))[sub];
        if (h5) rF = ((const float4*)(zin + (size_t)r5 * OUT_CH))[sub];
        ACC8(rA); ACC8(rB); ACC8(rC); ACC8(rD); ACC8(rE); ACC8(rF);
    }
    {   // last 6 batches
        float4 rA = make_float4(0.f, 0.f, 0.f, 0.f);
        float4 rB = make_float4(0.f, 0.f, 0.f, 0.f);
        float4 rC = make_float4(0.f, 0.f, 0.f, 0.f);
        float4 rD = make_float4(0.f, 0.f, 0.f, 0.f);
        float4 rE = make_float4(0.f, 0.f, 0.f, 0.f);
        float4 rF = make_float4(0.f, 0.f, 0.f, 0.f);
        if (h6)  rA = ((const float4*)(zin + (size_t)r6 * OUT_CH))[sub];
        if (h7)  rB = ((const float4*)(zin + (size_t)r7 * OUT_CH))[sub];
        if (h8)  rC = ((const float4*)(zin + (size_t)r8 * OUT_CH))[sub];
        if (h9)  rD = ((const float4*)(zin + (size_t)r9 * OUT_CH))[sub];
        if (h10) rE = ((const float4*)(zin + (size_t)r10 * OUT_CH))[sub];
        if (h11) rF = ((const float4*)(zin + (size_t)r11 * OUT_CH))[sub];
        ACC8(rA); ACC8(rB); ACC8(rC); ACC8(rD); ACC8(rE); ACC8(rF);
    }
    if (e - s > 24) {          // rare per node (~8%): pipelined 2-batch tail
        int j0 = s + 24 + grp, j1 = j0 + 2;
        bool g0 = j0 < e, g1 = j1 < e;
        int q0 = g0 ? (int)eidx[j0] : 0;
        int q1 = g1 ? (int)eidx[j1] : 0;
        while (g0) {           // g1 implies g0
            int k0 = j0 + 4, k1 = j1 + 4;
            bool f0 = k0 < e, f1 = k1 < e;
            int p0 = f0 ? (int)eidx[k0] : 0;
            int p1 = f1 ? (int)eidx[k1] : 0;
            float4 xA = make_float4(0.f, 0.f, 0.f, 0.f);
            float4 xB = make_float4(0.f, 0.f, 0.f, 0.f);
            if (g0) xA = ((const float4*)(zin + (size_t)q0 * OUT_CH))[sub];
            if (g1) xB = ((const float4*)(zin + (size_t)q1 * OUT_CH))[sub];
            ACC8(xA); ACC8(xB);
            j0 = k0; j1 = k1; q0 = p0; q1 = p1; g0 = f0; g1 = f1;
        }
    }
    // reduce the 2 edge slots (lanes differing in bit 3; stays in quarter-wave)
    a0 += __shfl_xor(a0, 8, 64); a1 += __shfl_xor(a1, 8, 64);
    a2 += __shfl_xor(a2, 8, 64); a3 += __shfl_xor(a3, 8, 64);
    a4 += __shfl_xor(a4, 8, 64); a5 += __shfl_xor(a5, 8, 64);
    a6 += __shfl_xor(a6, 8, 64); a7 += __shfl_xor(a7, 8, 64);
    if (grp == 0) {
        if (MODE == 0) {
            float sc = dv * dv;
            union { __half2 h[4]; float4 f; } u;
            u.h[0] = __floats2half2_rn(sc * a0, sc * a1);
            u.h[1] = __floats2half2_rn(sc * a2, sc * a3);
            u.h[2] = __floats2half2_rn(sc * a4, sc * a5);
            u.h[3] = __floats2half2_rn(sc * a6, sc * a7);
            ((float4*)((__half*)out + (size_t)v * OUT_CH))[sub] = u.f;
        } else {
            const float4* bp = (const float4*)(bias + sub * 8);
            float4 b0 = bp[0], b1 = bp[1];
            float* op = (float*)out + (size_t)v * OUT_CH + sub * 8;
            *(float4*)op = make_float4(fmaf(dv, a0, b0.x), fmaf(dv, a1, b0.y),
                                       fmaf(dv, a2, b0.z), fmaf(dv, a3, b0.w));
            *(float4*)(op + 4) = make_float4(fmaf(dv, a4, b1.x), fmaf(dv, a5, b1.y),
                                             fmaf(dv, a6, b1.z), fmaf(dv, a7, b1.w));
        }
    }
}

extern "C" void kernel_launch(void* const* d_in, const int* in_sizes, int n_in,
                              void* d_out, int out_size, void* d_ws, size_t ws_size,
                              hipStream_t stream) {
    const float* x = (const float*)d_in[0];
    const int* ei = (const int*)d_in[1];
    const float* W = (const float*)d_in[2];
    const float* b = (const float*)d_in[3];
    int n = in_sizes[0] / IN_CH;   // 50000
    int E = in_sizes[1] / 2;       // 800000
    const int* row = ei;           // edge_index[0] = source
    const int* col = ei + E;       // edge_index[1] = target

    char* ws = (char*)d_ws;
    size_t o = 0;
    auto alloc = [&](size_t bytes) -> void* {
        void* p = ws + o;
        o += (bytes + 255) & ~(size_t)255;
        return p;
    };
    int nbkt = (n + 255) >> 8;      // 196
    int chunk = (E + NB - 1) / NB;  // 3125

    int*            blkcnt = (int*)alloc((size_t)NB * 256 * 4);
    int*            rawcnt = (int*)alloc((size_t)NB * 256 * 4);
    int*            totals = (int*)alloc(256 * 4);
    unsigned int*   tmp    = (unsigned int*)alloc((size_t)E * 4);
    int*            off    = (int*)alloc((size_t)(n + 1) * 4);
    float*          dis    = (float*)alloc((size_t)n * 4);
    unsigned short* eidx   = (unsigned short*)alloc((size_t)E * 2);
    __half*         zA     = (__half*)alloc((size_t)n * OUT_CH * 2);
    __half*         zB     = (__half*)alloc((size_t)n * OUT_CH * 2);

    histo_kernel<<<NB, 512, 0, stream>>>(col, blkcnt, rawcnt, E, chunk);
    scanblk_kernel<<<nbkt, 256, 0, stream>>>(blkcnt, totals);
    bucket_scatter_kernel<<<NB, 512, 0, stream>>>(row, col, blkcnt, rawcnt, totals, tmp, E, chunk, nbkt);
    bucket_sort_kernel<<<nbkt, 512, 0, stream>>>(tmp, totals, off, dis, eidx, nbkt, E, n);
    gemm_kernel<<<(n + 63) / 64, 256, 0, stream>>>(x, W, dis, zA, n);
    int hopBlocks = (n + 15) / 16;   // quarter-wave per node (4 nodes/wave)
    hop_kernel<0><<<hopBlocks, 256, 0, stream>>>(zA, zB, eidx, off, dis, nullptr, n);
    hop_kernel<1><<<hopBlocks, 256, 0, stream>>>(zB, d_out, eidx, off, dis, b, n);
}